// Round 1
// baseline (41.434 us; speedup 1.0000x reference)
//
#include <hip/hip_runtime.h>

#define NTRAIN 200000
#define NB     256     // batch
#define BIT    64
#define MAXS   30
#define MVAL   128.0f  // M = 2*BIT
#define ALPHA  0.01f

// Block b handles batch row b:
//   1) virtual-scatter pool build: first MAXS ascending j with Yeff[j]==y[b]
//   2) gather Ueff rows of the pool into LDS
//   3) pair loss of ALL 256 u-rows vs this block's pool entries
// writes partial[b] (unscaled pair sum) and cnt[b].
__global__ __launch_bounds__(256) void dsh_row_kernel(
    const float* __restrict__ u, const int* __restrict__ y,
    const int* __restrict__ ind, const float* __restrict__ U,
    const float* __restrict__ Y,
    float* __restrict__ partial, int* __restrict__ cntout)
{
    __shared__ float up_l[MAXS * BIT];
    __shared__ int   ind_l[NB];
    __shared__ int   y_l[NB];
    __shared__ int   ovr[256];
    __shared__ int   pool[MAXS];
    __shared__ int   povr[MAXS];
    __shared__ int   wcnt[4];
    __shared__ float red[4];

    const int t    = threadIdx.x;
    const int b    = blockIdx.x;
    const int lane = t & 63;
    const int wave = t >> 6;

    ind_l[t] = ind[t];
    y_l[t]   = y[t];
    __syncthreads();

    const float target = (float)y_l[b];

    // ---- pool build: chunked scan with per-chunk scatter-override ----
    int count = 0;
    for (int base = 0; base < NTRAIN; base += 256) {
        ovr[t] = -1;
        __syncthreads();
        unsigned rel = (unsigned)(ind_l[t] - base);
        if (rel < 256u) ovr[rel] = t;     // ind distinct -> no write conflict
        __syncthreads();
        const int j = base + t;
        bool m = false;
        if (j < NTRAIN) {
            int o = ovr[t];
            float yj = (o >= 0) ? (float)y_l[o] : Y[j];
            m = (yj == target);
        }
        unsigned long long bal = __ballot(m);
        if (lane == 0) wcnt[wave] = (int)__popcll(bal);
        __syncthreads();
        int pre = count;
        #pragma unroll
        for (int w = 0; w < 4; ++w) if (w < wave) pre += wcnt[w];
        int rank = pre + (int)__popcll(bal & ((1ull << lane) - 1ull));
        if (m && rank < MAXS) pool[rank] = j;
        count += wcnt[0] + wcnt[1] + wcnt[2] + wcnt[3];
        __syncthreads();                  // protects ovr/wcnt reuse + pool writes
        if (count >= MAXS) break;         // uniform (count from shared wcnt)
    }
    const int cnt = (count < MAXS) ? count : MAXS;

    // ---- resolve which pool entries are overridden by the batch scatter ----
    if (t < MAXS) povr[t] = -1;
    __syncthreads();
    for (int k = 0; k < cnt; ++k)
        if (ind_l[t] == pool[k]) povr[k] = t;   // at most one t matches
    __syncthreads();

    // ---- gather Ueff rows for the pool into LDS ----
    for (int idx = t; idx < MAXS * BIT; idx += 256) {
        const int pp = idx >> 6;
        const int d  = idx & 63;
        float v = 0.f;
        if (pp < cnt) {
            const int ov = povr[pp];
            v = (ov >= 0) ? u[ov * BIT + d] : U[pool[pp] * BIT + d];
        }
        up_l[idx] = v;
    }
    __syncthreads();

    // ---- pair loss: thread t = batch row i, vs this block's pool ----
    float4 ur[16];
    {
        const float4* urp = (const float4*)(u + t * BIT);
        #pragma unroll
        for (int q = 0; q < 16; ++q) ur[q] = urp[q];
    }
    const bool same = (y_l[t] == y_l[b]);
    float acc = 0.f;
    for (int pp = 0; pp < cnt; ++pp) {
        const float4* up = (const float4*)(up_l + pp * BIT);  // uniform -> LDS broadcast
        float d0 = 0.f, d1 = 0.f, d2 = 0.f, d3 = 0.f;
        #pragma unroll
        for (int q = 0; q < 16; ++q) {
            float4 v = up[q];
            float a0 = ur[q].x - v.x; d0 += a0 * a0;
            float a1 = ur[q].y - v.y; d1 += a1 * a1;
            float a2 = ur[q].z - v.z; d2 += a2 * a2;
            float a3 = ur[q].w - v.w; d3 += a3 * a3;
        }
        const float dist = (d0 + d1) + (d2 + d3);
        acc += same ? dist : fmaxf(MVAL - dist, 0.f);
    }

    // ---- block reduce ----
    #pragma unroll
    for (int off = 32; off; off >>= 1) acc += __shfl_down(acc, off, 64);
    if (lane == 0) red[wave] = acc;
    __syncthreads();
    if (t == 0) {
        partial[b] = red[0] + red[1] + red[2] + red[3];
        cntout[b]  = cnt;
    }
}

__global__ __launch_bounds__(256) void dsh_final_kernel(
    const float* __restrict__ u,
    const float* __restrict__ partial, const int* __restrict__ cnt,
    float* __restrict__ out)
{
    const int t = threadIdx.x;
    const int lane = t & 63, wave = t >> 6;
    __shared__ float redp[4], reda[4];
    __shared__ int   redc[4];

    float p = partial[t];
    int   c = cnt[t];
    float a = 0.f;
    #pragma unroll
    for (int r = 0; r < 64; ++r) {       // 16384 elements, coalesced
        float v = u[r * 256 + t];
        a += fabsf(fabsf(v) - 1.0f);
    }
    #pragma unroll
    for (int off = 32; off; off >>= 1) {
        p += __shfl_down(p, off, 64);
        a += __shfl_down(a, off, 64);
        c += __shfl_down(c, off, 64);
    }
    if (lane == 0) { redp[wave] = p; reda[wave] = a; redc[wave] = c; }
    __syncthreads();
    if (t == 0) {
        float P = redp[0] + redp[1] + redp[2] + redp[3];
        float A = reda[0] + reda[1] + reda[2] + reda[3];
        int   S = redc[0] + redc[1] + redc[2] + redc[3];
        float loss1 = 0.5f * P / (256.0f * (float)S);
        float loss2 = ALPHA * (A * (1.0f / 16384.0f));
        out[0] = loss1 + loss2;
    }
}

extern "C" void kernel_launch(void* const* d_in, const int* in_sizes, int n_in,
                              void* d_out, int out_size, void* d_ws, size_t ws_size,
                              hipStream_t stream) {
    const float* u   = (const float*)d_in[0];
    const int*   y   = (const int*)d_in[1];
    const int*   ind = (const int*)d_in[2];
    const float* U   = (const float*)d_in[3];
    const float* Y   = (const float*)d_in[4];
    float* out = (float*)d_out;

    float* partial = (float*)d_ws;
    int*   cnt     = (int*)((char*)d_ws + NB * sizeof(float));

    dsh_row_kernel<<<dim3(NB), dim3(256), 0, stream>>>(u, y, ind, U, Y, partial, cnt);
    dsh_final_kernel<<<dim3(1), dim3(256), 0, stream>>>(u, partial, cnt, out);
}

// Round 2
// 27.041 us; speedup vs baseline: 1.5323x; 1.5323x over previous
//
#include <hip/hip_runtime.h>

#define NTRAIN 200000
#define NB     256     // batch
#define BIT    64
#define MAXS   30
#define HALF   15      // pool entries per block (2 blocks per class)
#define NCLS   100
#define CHUNK  4096    // scan entries per block-iteration
#define PERT   16      // scan entries per thread (CHUNK/256)
#define MVAL   128.0f  // M = 2*BIT
#define ALPHA  0.01f

// Block (c, h): build the first-MAXS ascending pool for class c over the
// virtually-scattered bank, then compute pair loss of all 256 u-rows vs
// pool entries [h*HALF, ...), weighted by multiplicity of class c in y.
__global__ __launch_bounds__(256) void dsh_class_kernel(
    const float* __restrict__ u, const int* __restrict__ y,
    const int* __restrict__ ind, const float* __restrict__ U,
    const float* __restrict__ Y,
    float* __restrict__ partial, int* __restrict__ cntw)
{
    __shared__ int   ovr[CHUNK];          // 16 KB scatter-override map
    __shared__ float up_l[HALF * BIT];
    __shared__ int   ind_l[NB];
    __shared__ int   y_l[NB];
    __shared__ int   pool[MAXS];
    __shared__ int   povr[MAXS];
    __shared__ int   wsum[4];
    __shared__ float red[4];

    const int t    = threadIdx.x;
    const int c    = blockIdx.x;          // class
    const int h    = blockIdx.y;          // pool half
    const int lane = t & 63;
    const int wave = t >> 6;

    ind_l[t] = ind[t];
    y_l[t]   = y[t];
    __syncthreads();

    // ---- multiplicity of class c in the batch ----
    unsigned long long bal = __ballot(y_l[t] == c);
    if (lane == 0) wsum[wave] = (int)__popcll(bal);
    __syncthreads();
    const int mult = wsum[0] + wsum[1] + wsum[2] + wsum[3];
    __syncthreads();
    if (mult == 0) {                      // class absent: contributes nothing
        if (t == 0) {
            partial[c * 2 + h] = 0.f;
            if (h == 0) cntw[c] = 0;
        }
        return;
    }

    const float cf = (float)c;

    // ---- pool build: 4096-wide chunks, ordered prefix-scan ranking ----
    int count = 0;
    for (int base = 0; base < NTRAIN && count < MAXS; base += CHUNK) {
        // clear override map (conflict-free int4 stores)
        #pragma unroll
        for (int k = 0; k < 4; ++k)
            ((int4*)ovr)[t + 256 * k] = make_int4(-1, -1, -1, -1);
        __syncthreads();
        unsigned rel = (unsigned)(ind_l[t] - base);
        if (rel < (unsigned)CHUNK) ovr[rel] = t;   // ind distinct -> no conflict
        __syncthreads();

        const int s = base + t * PERT;
        int mbits = 0, mcnt = 0;
        if (s < NTRAIN) {                 // NTRAIN % PERT == 0 -> full vector ok
            float4 yv[4];
            const float4* yp = (const float4*)(Y + s);
            #pragma unroll
            for (int q = 0; q < 4; ++q) yv[q] = yp[q];
            const float* yf = (const float*)yv;
            #pragma unroll
            for (int k = 0; k < PERT; ++k) {
                int o = ovr[t * PERT + k];
                float yj = (o >= 0) ? (float)y_l[o] : yf[k];
                if (yj == cf) { mbits |= (1 << k); ++mcnt; }
            }
        }
        // ordered inclusive scan of mcnt over the block
        int x = mcnt;
        #pragma unroll
        for (int off = 1; off < 64; off <<= 1) {
            int v = __shfl_up(x, off, 64);
            if (lane >= off) x += v;
        }
        if (lane == 63) wsum[wave] = x;
        __syncthreads();
        int wpre = 0;
        #pragma unroll
        for (int w = 0; w < 4; ++w) if (w < wave) wpre += wsum[w];
        int r = count + wpre + (x - mcnt);          // exclusive global rank
        #pragma unroll
        for (int k = 0; k < PERT; ++k) {
            if ((mbits >> k) & 1) {
                if (r < MAXS) pool[r] = s + k;
                ++r;
            }
        }
        count += wsum[0] + wsum[1] + wsum[2] + wsum[3];
        __syncthreads();                  // pool/wsum settle before reuse/exit
    }
    const int cnt = (count < MAXS) ? count : MAXS;

    // ---- resolve batch-scatter overrides among pool entries ----
    if (t < MAXS) povr[t] = -1;
    __syncthreads();
    for (int k = 0; k < cnt; ++k)
        if (ind_l[t] == pool[k]) povr[k] = t;       // at most one t matches
    __syncthreads();

    // ---- gather Ueff rows for this block's half of the pool ----
    const int p0 = h * HALF;
    const int pe = (h == 0) ? ((cnt < HALF) ? cnt : HALF) : cnt;
    for (int idx = t; idx < HALF * BIT; idx += 256) {
        const int pp = p0 + (idx >> 6);
        const int d  = idx & 63;
        float v = 0.f;
        if (pp < pe) {
            const int ov = povr[pp];
            v = (ov >= 0) ? u[ov * BIT + d] : U[pool[pp] * BIT + d];
        }
        up_l[idx] = v;
    }
    __syncthreads();

    // ---- pair loss: thread t = batch row t, vs pool entries [p0, pe) ----
    float4 ur[16];
    {
        const float4* urp = (const float4*)(u + t * BIT);
        #pragma unroll
        for (int q = 0; q < 16; ++q) ur[q] = urp[q];
    }
    const bool same = (y_l[t] == c);
    float acc = 0.f;
    for (int pp = p0; pp < pe; ++pp) {
        const float4* up = (const float4*)(up_l + (pp - p0) * BIT);
        float d0 = 0.f, d1 = 0.f, d2 = 0.f, d3 = 0.f;
        #pragma unroll
        for (int q = 0; q < 16; ++q) {
            float4 v = up[q];
            float a0 = ur[q].x - v.x; d0 += a0 * a0;
            float a1 = ur[q].y - v.y; d1 += a1 * a1;
            float a2 = ur[q].z - v.z; d2 += a2 * a2;
            float a3 = ur[q].w - v.w; d3 += a3 * a3;
        }
        const float dist = (d0 + d1) + (d2 + d3);
        acc += same ? dist : fmaxf(MVAL - dist, 0.f);
    }

    // ---- block reduce, weight by multiplicity ----
    #pragma unroll
    for (int off = 32; off; off >>= 1) acc += __shfl_down(acc, off, 64);
    if (lane == 0) red[wave] = acc;
    __syncthreads();
    if (t == 0) {
        partial[c * 2 + h] = (float)mult * (red[0] + red[1] + red[2] + red[3]);
        if (h == 0) cntw[c] = mult * cnt;
    }
}

__global__ __launch_bounds__(256) void dsh_final_kernel(
    const float* __restrict__ u,
    const float* __restrict__ partial, const int* __restrict__ cntw,
    float* __restrict__ out)
{
    const int t = threadIdx.x;
    const int lane = t & 63, wave = t >> 6;
    __shared__ float redp[4], reda[4];
    __shared__ int   redc[4];

    float p = (t < 2 * NCLS) ? partial[t] : 0.f;
    int   c = (t < NCLS) ? cntw[t] : 0;
    float a = 0.f;
    #pragma unroll
    for (int k = 0; k < 16; ++k) {        // 16384 floats, float4-coalesced
        float4 v = ((const float4*)u)[t + 256 * k];
        a += fabsf(fabsf(v.x) - 1.0f) + fabsf(fabsf(v.y) - 1.0f)
           + fabsf(fabsf(v.z) - 1.0f) + fabsf(fabsf(v.w) - 1.0f);
    }
    #pragma unroll
    for (int off = 32; off; off >>= 1) {
        p += __shfl_down(p, off, 64);
        a += __shfl_down(a, off, 64);
        c += __shfl_down(c, off, 64);
    }
    if (lane == 0) { redp[wave] = p; reda[wave] = a; redc[wave] = c; }
    __syncthreads();
    if (t == 0) {
        float P = redp[0] + redp[1] + redp[2] + redp[3];
        float A = reda[0] + reda[1] + reda[2] + reda[3];
        int   S = redc[0] + redc[1] + redc[2] + redc[3];
        float loss1 = 0.5f * P / (256.0f * (float)S);
        float loss2 = ALPHA * (A * (1.0f / 16384.0f));
        out[0] = loss1 + loss2;
    }
}

extern "C" void kernel_launch(void* const* d_in, const int* in_sizes, int n_in,
                              void* d_out, int out_size, void* d_ws, size_t ws_size,
                              hipStream_t stream) {
    const float* u   = (const float*)d_in[0];
    const int*   y   = (const int*)d_in[1];
    const int*   ind = (const int*)d_in[2];
    const float* U   = (const float*)d_in[3];
    const float* Y   = (const float*)d_in[4];
    float* out = (float*)d_out;

    float* partial = (float*)d_ws;                         // [2*NCLS]
    int*   cntw    = (int*)((char*)d_ws + 2 * NCLS * sizeof(float)); // [NCLS]

    dsh_class_kernel<<<dim3(NCLS, 2), dim3(256), 0, stream>>>(
        u, y, ind, U, Y, partial, cntw);
    dsh_final_kernel<<<dim3(1), dim3(256), 0, stream>>>(u, partial, cntw, out);
}

// Round 3
// 22.087 us; speedup vs baseline: 1.8759x; 1.2243x over previous
//
#include <hip/hip_runtime.h>

#define NTRAIN 200000
#define NB     256
#define BIT    64
#define MAXS   30
#define NCLS   100
#define ESPL   8            // entry-chunks per class
#define EPB    4            // pool entries per block (8*4 >= 30)
#define CHUNK  4096
#define PERT   16
#define NREG   16           // regularizer blocks (1024 u-elems each)
#define MVAL   128.0f
#define ALPHA  0.01f

// Blocks [0, 800): (class c, entry-chunk e) — scan for class pool, compute
// pair loss of all 256 rows vs pool entries [4e, min(4e+4, cnt)), x mult.
// Blocks [800, 816): partial sums of | |u| - 1 |.
__global__ __launch_bounds__(256) void dsh_main_kernel(
    const float* __restrict__ u, const int* __restrict__ y,
    const int* __restrict__ ind, const float* __restrict__ U,
    const float* __restrict__ Y,
    float* __restrict__ partial, int* __restrict__ cntw)
{
    __shared__ int   ovrT[CHUNK];       // transposed [16][256] override map
    __shared__ float up_l[EPB * BIT];
    __shared__ int   ind_l[NB];
    __shared__ int   y_l[NB];
    __shared__ int   pool[MAXS];
    __shared__ int   povr[EPB];
    __shared__ int   wsum[4];
    __shared__ float red[4];

    const int t    = threadIdx.x;
    const int j    = blockIdx.x;
    const int lane = t & 63;
    const int wave = t >> 6;

    if (j >= NCLS * ESPL) {             // ---- regularizer partials ----
        const int q = j - NCLS * ESPL;
        float4 v = ((const float4*)u)[q * 256 + t];
        float a = fabsf(fabsf(v.x) - 1.f) + fabsf(fabsf(v.y) - 1.f)
                + fabsf(fabsf(v.z) - 1.f) + fabsf(fabsf(v.w) - 1.f);
        #pragma unroll
        for (int off = 32; off; off >>= 1) a += __shfl_down(a, off, 64);
        if (lane == 0) red[wave] = a;
        __syncthreads();
        if (t == 0) partial[j] = red[0] + red[1] + red[2] + red[3];
        return;
    }

    const int c = j >> 3;               // class
    const int e = j & 7;                // entry-chunk

    ind_l[t] = ind[t];
    y_l[t]   = y[t];
    __syncthreads();

    // multiplicity of class c in the batch
    unsigned long long bal = __ballot(y_l[t] == c);
    if (lane == 0) wsum[wave] = (int)__popcll(bal);
    __syncthreads();
    const int mult = wsum[0] + wsum[1] + wsum[2] + wsum[3];
    if (mult == 0) {
        if (t == 0) { partial[j] = 0.f; if (e == 0) cntw[c] = 0; }
        return;
    }
    __syncthreads();                    // wsum reused below

    const float cf = (float)c;

    // ---- scan: first MAXS ascending matches over virtually-scattered bank ----
    int count = 0;
    for (int base = 0; base < NTRAIN && count < MAXS; base += CHUNK) {
        const int s = base + t * PERT;
        float yf[PERT];
        if (s < NTRAIN) {               // issue Y loads before LDS work
            #pragma unroll
            for (int q2 = 0; q2 < 4; ++q2)
                ((float4*)yf)[q2] = ((const float4*)(Y + s))[q2];
        }
        #pragma unroll
        for (int k2 = 0; k2 < 4; ++k2)
            ((int4*)ovrT)[t + 256 * k2] = make_int4(-1, -1, -1, -1);
        __syncthreads();
        unsigned rel = (unsigned)(ind_l[t] - base);
        if (rel < (unsigned)CHUNK)
            ovrT[(rel & 15) * 256 + (rel >> 4)] = t;   // ind distinct
        __syncthreads();

        unsigned mbits = 0; int mcnt = 0;
        if (s < NTRAIN) {
            #pragma unroll
            for (int k2 = 0; k2 < PERT; ++k2) {
                int o = ovrT[k2 * 256 + t];            // lane-stride-1: no conflict
                bool m = (o >= 0) ? (y_l[o] == c) : (yf[k2] == cf);
                if (m) { mbits |= (1u << k2); ++mcnt; }
            }
        }
        // ordered inclusive block scan of mcnt
        int x = mcnt;
        #pragma unroll
        for (int off = 1; off < 64; off <<= 1) {
            int v = __shfl_up(x, off, 64);
            if (lane >= off) x += v;
        }
        if (lane == 63) wsum[wave] = x;
        __syncthreads();
        int wpre = 0;
        #pragma unroll
        for (int w = 0; w < 4; ++w) if (w < wave) wpre += wsum[w];
        int r = count + wpre + (x - mcnt);             // exclusive global rank
        #pragma unroll
        for (int k2 = 0; k2 < PERT; ++k2) {
            if ((mbits >> k2) & 1u) {
                if (r < MAXS) pool[r] = s + k2;
                ++r;
            }
        }
        count += wsum[0] + wsum[1] + wsum[2] + wsum[3];
        __syncthreads();
    }
    const int cnt = (count < MAXS) ? count : MAXS;

    // ---- this block's entries: overrides + gather ----
    const int p0 = e * EPB;
    const int pe = (p0 + EPB < cnt) ? p0 + EPB : cnt;
    if (t < EPB) povr[t] = -1;
    __syncthreads();
    for (int k2 = p0; k2 < pe; ++k2)
        if (ind_l[t] == pool[k2]) povr[k2 - p0] = t;   // at most one t
    __syncthreads();
    {
        const int pp = t >> 6;          // local entry 0..3
        const int d  = t & 63;
        float v = 0.f;
        if (p0 + pp < pe) {
            const int ov = povr[pp];
            v = (ov >= 0) ? u[ov * BIT + d] : U[pool[p0 + pp] * BIT + d];
        }
        up_l[t] = v;
    }
    __syncthreads();

    // ---- pair loss: thread t = batch row t vs entries [p0, pe) ----
    float4 ur[16];
    {
        const float4* urp = (const float4*)(u + t * BIT);
        #pragma unroll
        for (int q2 = 0; q2 < 16; ++q2) ur[q2] = urp[q2];
    }
    const bool same = (y_l[t] == c);
    const int npool = pe - p0;
    float acc = 0.f;
    for (int pp = 0; pp < npool; ++pp) {
        const float4* up = (const float4*)(up_l + pp * BIT);
        float d0 = 0.f, d1 = 0.f, d2 = 0.f, d3 = 0.f;
        #pragma unroll
        for (int q2 = 0; q2 < 16; ++q2) {
            float4 v = up[q2];
            float a0 = ur[q2].x - v.x; d0 += a0 * a0;
            float a1 = ur[q2].y - v.y; d1 += a1 * a1;
            float a2 = ur[q2].z - v.z; d2 += a2 * a2;
            float a3 = ur[q2].w - v.w; d3 += a3 * a3;
        }
        const float dist = (d0 + d1) + (d2 + d3);
        acc += same ? dist : fmaxf(MVAL - dist, 0.f);
    }

    #pragma unroll
    for (int off = 32; off; off >>= 1) acc += __shfl_down(acc, off, 64);
    if (lane == 0) red[wave] = acc;
    __syncthreads();
    if (t == 0) {
        partial[j] = (float)mult * (red[0] + red[1] + red[2] + red[3]);
        if (e == 0) cntw[c] = mult * cnt;
    }
}

__global__ __launch_bounds__(256) void dsh_final_kernel(
    const float* __restrict__ partial, const int* __restrict__ cntw,
    float* __restrict__ out)
{
    const int t = threadIdx.x;
    const int lane = t & 63, wave = t >> 6;
    __shared__ float redp[4], reda[4];
    __shared__ int   redc[4];

    float p = 0.f, a = 0.f;
    #pragma unroll
    for (int k = 0; k < 4; ++k) {
        const int idx = t + 256 * k;
        if (idx < NCLS * ESPL)            p += partial[idx];
        else if (idx < NCLS * ESPL + NREG) a += partial[idx];
    }
    int cc = (t < NCLS) ? cntw[t] : 0;
    #pragma unroll
    for (int off = 32; off; off >>= 1) {
        p  += __shfl_down(p,  off, 64);
        a  += __shfl_down(a,  off, 64);
        cc += __shfl_down(cc, off, 64);
    }
    if (lane == 0) { redp[wave] = p; reda[wave] = a; redc[wave] = cc; }
    __syncthreads();
    if (t == 0) {
        float P = redp[0] + redp[1] + redp[2] + redp[3];
        float A = reda[0] + reda[1] + reda[2] + reda[3];
        int   S = redc[0] + redc[1] + redc[2] + redc[3];
        out[0] = 0.5f * P / (256.0f * (float)S) + ALPHA * (A * (1.0f / 16384.0f));
    }
}

extern "C" void kernel_launch(void* const* d_in, const int* in_sizes, int n_in,
                              void* d_out, int out_size, void* d_ws, size_t ws_size,
                              hipStream_t stream) {
    const float* u   = (const float*)d_in[0];
    const int*   y   = (const int*)d_in[1];
    const int*   ind = (const int*)d_in[2];
    const float* U   = (const float*)d_in[3];
    const float* Y   = (const float*)d_in[4];
    float* out = (float*)d_out;

    float* partial = (float*)d_ws;                    // [816]
    int*   cntw    = (int*)((char*)d_ws + 4096);      // [100]

    dsh_main_kernel<<<dim3(NCLS * ESPL + NREG), dim3(256), 0, stream>>>(
        u, y, ind, U, Y, partial, cntw);
    dsh_final_kernel<<<dim3(1), dim3(256), 0, stream>>>(partial, cntw, out);
}